// Round 3
// baseline (821.199 us; speedup 1.0000x reference)
//
#include <hip/hip_runtime.h>
#include <hip/hip_bf16.h>

// Problem constants (fixed by the reference's setup_inputs).
constexpr int VOCAB    = 32000;
constexpr int NUM_NEW  = 512;
constexpr int HIDDEN   = 4096;
constexpr int PROF_DIM = 64;
constexpr int MLP_HID  = 256;

typedef float f32x4 __attribute__((ext_vector_type(4)));

// ---------------------------------------------------------------------------
// Fused kernel: one block per output row.
//   non-tool row: out[row][:] = emb[id][:]            (pure streaming copy)
//   tool row:     out[row][:] = sem[rel][:] + relu(prof[rel]@W1+b1)@W2 + b2
// Only ~1.6% of rows are tool rows, so the MLP path (inline, W2 L2/L3-
// resident, ~1 tool block per CU running under the copy-path shadow) is off
// the critical BW path. No workspace, one launch.
// Stores are non-temporal: the 256 MiB write stream must not evict the
// emb-row gather set (~206 MiB unique, L3-resident) from cache.
// ---------------------------------------------------------------------------
__global__ __launch_bounds__(256) void fused_embed_kernel(
    const int*   __restrict__ input_ids,      // [B*S]
    const float* __restrict__ emb_weight,     // [VOCAB+NUM_NEW, HIDDEN]
    const float* __restrict__ tool_semantics, // [NUM_NEW, HIDDEN]
    const float* __restrict__ profiles,       // [NUM_NEW, PROF_DIM]
    const float* __restrict__ W1,             // [PROF_DIM, MLP_HID]
    const float* __restrict__ b1,             // [MLP_HID]
    const float* __restrict__ W2,             // [MLP_HID, HIDDEN]
    const float* __restrict__ b2,             // [HIDDEN]
    const int*   __restrict__ new_start_ptr,  // [1]
    float*       __restrict__ out)            // [B*S, HIDDEN]
{
    __shared__ float prof_s[PROF_DIM];   // 256 B
    __shared__ float h_s[MLP_HID];       // 1 KiB

    const int row       = blockIdx.x;
    const int t         = threadIdx.x;       // 0..255
    const int id        = input_ids[row];    // uniform per block
    const int new_start = *new_start_ptr;

    f32x4* d = (f32x4*)(out + (size_t)row * HIDDEN);

    if (id < new_start) {
        // ---- streaming copy path (98.4% of blocks) ----
        const f32x4* s = (const f32x4*)(emb_weight + (size_t)id * HIDDEN);
        // HIDDEN/4 = 1024 float4 slots; 256 threads -> 4 each, loads batched.
        f32x4 v0 = s[t];
        f32x4 v1 = s[t + 256];
        f32x4 v2 = s[t + 512];
        f32x4 v3 = s[t + 768];
        __builtin_nontemporal_store(v0, d + t);
        __builtin_nontemporal_store(v1, d + t + 256);
        __builtin_nontemporal_store(v2, d + t + 512);
        __builtin_nontemporal_store(v3, d + t + 768);
        return;
    }

    // ---- tool-token path (~258 of 16384 blocks) ----
    int rel = id - new_start;
    if (rel > NUM_NEW - 1) rel = NUM_NEW - 1;  // match jnp.clip

    // Stage the profile row (64 floats) into LDS.
    if (t < PROF_DIM) prof_s[t] = profiles[rel * PROF_DIM + t];
    __syncthreads();

    // Layer 1: thread t computes h[t] = relu(b1[t] + prof . W1[:,t]).
    // W1[p*MLP_HID + t] is coalesced across t; prof_s[p] is an LDS broadcast.
    {
        float acc = b1[t];
#pragma unroll
        for (int p = 0; p < PROF_DIM; ++p)
            acc = fmaf(prof_s[p], W1[p * MLP_HID + t], acc);
        h_s[t] = fmaxf(acc, 0.0f);
    }
    __syncthreads();

    // Layer 2 + epilogue: thread t owns float4 columns {t, t+256, t+512, t+768}.
    // W2 row reads are fully coalesced (block reads all 4 MiB of W2; W2 is
    // L2/L3-resident since every tool block reads the same matrix).
    const f32x4* sem4 = (const f32x4*)(tool_semantics + (size_t)rel * HIDDEN);
    const f32x4* b2_4 = (const f32x4*)b2;
    const f32x4* W2_4 = (const f32x4*)W2;

    f32x4 acc0 = sem4[t]       + b2_4[t];
    f32x4 acc1 = sem4[t + 256] + b2_4[t + 256];
    f32x4 acc2 = sem4[t + 512] + b2_4[t + 512];
    f32x4 acc3 = sem4[t + 768] + b2_4[t + 768];

    for (int k = 0; k < MLP_HID; ++k) {
        const float hv = h_s[k];              // LDS broadcast, free
        const f32x4* w2row = W2_4 + (size_t)k * (HIDDEN / 4);
        const f32x4 w0 = w2row[t];
        const f32x4 w1 = w2row[t + 256];
        const f32x4 w2v = w2row[t + 512];
        const f32x4 w3 = w2row[t + 768];
        acc0 += hv * w0;
        acc1 += hv * w1;
        acc2 += hv * w2v;
        acc3 += hv * w3;
    }

    __builtin_nontemporal_store(acc0, d + t);
    __builtin_nontemporal_store(acc1, d + t + 256);
    __builtin_nontemporal_store(acc2, d + t + 512);
    __builtin_nontemporal_store(acc3, d + t + 768);
}

extern "C" void kernel_launch(void* const* d_in, const int* in_sizes, int n_in,
                              void* d_out, int out_size, void* d_ws, size_t ws_size,
                              hipStream_t stream) {
    const int*   input_ids      = (const int*)d_in[0];
    const float* emb_weight     = (const float*)d_in[1];
    const float* tool_semantics = (const float*)d_in[2];
    const float* profiles       = (const float*)d_in[3];
    const float* W1             = (const float*)d_in[4];
    const float* b1             = (const float*)d_in[5];
    const float* W2             = (const float*)d_in[6];
    const float* b2             = (const float*)d_in[7];
    const int*   new_start_ptr  = (const int*)d_in[8];
    float*       out            = (float*)d_out;

    const int num_rows = in_sizes[0];  // B*S = 16384

    fused_embed_kernel<<<num_rows, 256, 0, stream>>>(
        input_ids, emb_weight, tool_semantics, profiles,
        W1, b1, W2, b2, new_start_ptr, out);
}